// Round 9
// baseline (234.574 us; speedup 1.0000x reference)
//
#include <hip/hip_runtime.h>

#define DIMSZ 300
#define CCH   16
#define NPTS  1048576

typedef _Float16 half4 __attribute__((ext_vector_type(4)));
typedef float    fvec4 __attribute__((ext_vector_type(4)));
typedef float    fvec2 __attribute__((ext_vector_type(2)));

__device__ __forceinline__ fvec4 h2f(half4 h) {
    fvec4 r;
    r.x = (float)h[0]; r.y = (float)h[1]; r.z = (float)h[2]; r.w = (float)h[3];
    return r;
}

// ---------------------------------------------------------------------------
// Planes: (C, HW) f32  ->  (HW, C) fp16.  blockIdx.y selects which plane.
// (Exact R2 version — best measured config.)
// ---------------------------------------------------------------------------
__global__ __launch_bounds__(256) void transpose_planes(
    const float* __restrict__ a, const float* __restrict__ b, const float* __restrict__ c,
    _Float16* __restrict__ ta, _Float16* __restrict__ tb, _Float16* __restrict__ tc)
{
    const int HW = DIMSZ * DIMSZ;
    const float* in  = (blockIdx.y == 0) ? a  : (blockIdx.y == 1) ? b  : c;
    _Float16*    out = (blockIdx.y == 0) ? ta : (blockIdx.y == 1) ? tb : tc;

    __shared__ float tile[64][CCH + 1];
    int pix0 = blockIdx.x * 64;
    int t = threadIdx.x;

    int p  = t & 63;
    int cg = t >> 6;   // 0..3
#pragma unroll
    for (int k = 0; k < 4; ++k) {
        int ch  = cg * 4 + k;
        int pix = pix0 + p;
        tile[p][ch] = (pix < HW) ? in[(size_t)ch * HW + pix] : 0.f;
    }
    __syncthreads();

    int q  = t & 3;
    int pr = t >> 2;   // 0..63
    int pix = pix0 + pr;
    if (pix < HW) {
        half4 h;
        h[0] = (_Float16)tile[pr][q * 4 + 0];
        h[1] = (_Float16)tile[pr][q * 4 + 1];
        h[2] = (_Float16)tile[pr][q * 4 + 2];
        h[3] = (_Float16)tile[pr][q * 4 + 3];
        ((half4*)out)[(size_t)pix * 4 + q] = h;
    }
}

// ---------------------------------------------------------------------------
// Lines: (C, H) f32 -> (H, C) f32.  Tiny.
// ---------------------------------------------------------------------------
__global__ __launch_bounds__(256) void transpose_lines(
    const float* __restrict__ a, const float* __restrict__ b, const float* __restrict__ c,
    float* __restrict__ ta, float* __restrict__ tb, float* __restrict__ tc)
{
    const float* in  = (blockIdx.y == 0) ? a  : (blockIdx.y == 1) ? b  : c;
    float*       out = (blockIdx.y == 0) ? ta : (blockIdx.y == 1) ? tb : tc;
    for (int idx = threadIdx.x; idx < DIMSZ * CCH; idx += 256) {
        int p  = idx >> 4;
        int ch = idx & 15;
        out[idx] = in[ch * DIMSZ + p];
    }
}

// ---------------------------------------------------------------------------
// Per-plane main kernel. K = output slot (0: yz*x, 1: xz*y, 2: xy*z).
// Identical to the best-measured R2 config EXCEPT the 4 plane-corner gathers
// are non-temporal: they are ~99% L1 misses (2.88 MB working set vs 32 KB L1)
// and we want them to bypass L1 allocation / its shallow miss queue and
// stream from L2 directly.
// ---------------------------------------------------------------------------
template <int K>
__global__ __launch_bounds__(256) void td_plane(
    const float* __restrict__ coords_plane,
    const float* __restrict__ coords_line,
    const _Float16* __restrict__ ptex,
    const float* __restrict__ ltex,
    float* __restrict__ out)
{
    int gid = blockIdx.x * 256 + threadIdx.x;
    int i = gid >> 2;
    int q = gid & 3;
    if (i >= NPTS) return;

    // out_x uses plane coords slice 1 (yz), out_y slice 2 (xz), out_z slice 0 (xy)
    constexpr int PC = (K == 0) ? 1 : (K == 1) ? 2 : 0;

    const fvec2* cp = (const fvec2*)coords_plane;
    const fvec2* cl = (const fvec2*)coords_line;
    fvec2 g  = cp[(size_t)PC * NPTS + i];
    float gl = cl[(size_t)K * NPTS + i].y;   // lines use grid[:,1] (W==1)

    // ---- plane bilinear (W = H = 300) ----
    float ix = (g.x + 1.f) * 0.5f * (float)(DIMSZ - 1);
    float iy = (g.y + 1.f) * 0.5f * (float)(DIMSZ - 1);
    float ix0f = floorf(ix), iy0f = floorf(iy);
    float wx = ix - ix0f, wy = iy - iy0f;
    int ix0 = min(max((int)ix0f, 0), DIMSZ - 1);
    int ix1 = min(ix0 + 1, DIMSZ - 1);
    int iy0 = min(max((int)iy0f, 0), DIMSZ - 1);
    int iy1 = min(iy0 + 1, DIMSZ - 1);

    const half4* t4 = (const half4*)ptex;
    size_t r0 = (size_t)iy0 * DIMSZ;
    size_t r1 = (size_t)iy1 * DIMSZ;
    half4 g00 = __builtin_nontemporal_load(&t4[(r0 + ix0) * 4 + q]);
    half4 g01 = __builtin_nontemporal_load(&t4[(r0 + ix1) * 4 + q]);
    half4 g10 = __builtin_nontemporal_load(&t4[(r1 + ix0) * 4 + q]);
    half4 g11 = __builtin_nontemporal_load(&t4[(r1 + ix1) * 4 + q]);
    fvec4 v00 = h2f(g00);
    fvec4 v01 = h2f(g01);
    fvec4 v10 = h2f(g10);
    fvec4 v11 = h2f(g11);

    float w00 = (1.f - wx) * (1.f - wy);
    float w01 = wx * (1.f - wy);
    float w10 = (1.f - wx) * wy;
    float w11 = wx * wy;

    fvec4 f = v00 * w00 + v01 * w01 + v10 * w10 + v11 * w11;

    // ---- line linear (H = 300), L1-resident: keep cached ----
    float lyv = (gl + 1.f) * 0.5f * (float)(DIMSZ - 1);
    float ly0f = floorf(lyv);
    float wl = lyv - ly0f;
    int l0 = min(max((int)ly0f, 0), DIMSZ - 1);
    int l1 = min(l0 + 1, DIMSZ - 1);

    const fvec4* l4 = (const fvec4*)ltex;
    fvec4 u0 = l4[(size_t)l0 * 4 + q];
    fvec4 u1 = l4[(size_t)l1 * 4 + q];
    fvec4 fl = u0 * (1.f - wl) + u1 * wl;

    fvec4* out4 = (fvec4*)out;
    out4[(size_t)K * NPTS * 4 + (size_t)i * 4 + q] = f * fl;
}

// ---------------------------------------------------------------------------
// Fallback (no usable ws): direct f32 gather from original (C,H,W) layout.
// ---------------------------------------------------------------------------
__global__ __launch_bounds__(256) void td_fallback(
    const float* __restrict__ coords_plane,
    const float* __restrict__ coords_line,
    const float* __restrict__ pxy, const float* __restrict__ pyz,
    const float* __restrict__ pxz,
    const float* __restrict__ lx, const float* __restrict__ ly,
    const float* __restrict__ lz,
    float* __restrict__ out)
{
    int gid = blockIdx.x * 256 + threadIdx.x;
    int i = gid >> 2;
    int q = gid & 3;
    if (i >= NPTS) return;

    const fvec2* cp = (const fvec2*)coords_plane;
    const fvec2* cl = (const fvec2*)coords_line;

    fvec4* out4 = (fvec4*)out;
    const float* planes[3] = {pyz, pxz, pxy};
    const float* lines[3]  = {lx, ly, lz};
    const int    pcs[3]    = {1, 2, 0};

#pragma unroll
    for (int k = 0; k < 3; ++k) {
        fvec2 g  = cp[(size_t)pcs[k] * NPTS + i];
        float gl = cl[(size_t)k * NPTS + i].y;

        float ix = (g.x + 1.f) * 0.5f * (float)(DIMSZ - 1);
        float iy = (g.y + 1.f) * 0.5f * (float)(DIMSZ - 1);
        float ix0f = floorf(ix), iy0f = floorf(iy);
        float wx = ix - ix0f, wy = iy - iy0f;
        int ix0 = min(max((int)ix0f, 0), DIMSZ - 1);
        int ix1 = min(ix0 + 1, DIMSZ - 1);
        int iy0 = min(max((int)iy0f, 0), DIMSZ - 1);
        int iy1 = min(iy0 + 1, DIMSZ - 1);
        float w00 = (1.f - wx) * (1.f - wy), w01 = wx * (1.f - wy);
        float w10 = (1.f - wx) * wy,         w11 = wx * wy;

        float lyv = (gl + 1.f) * 0.5f * (float)(DIMSZ - 1);
        float ly0f = floorf(lyv);
        float wl = lyv - ly0f;
        int l0 = min(max((int)ly0f, 0), DIMSZ - 1);
        int l1 = min(l0 + 1, DIMSZ - 1);

        const float* P = planes[k];
        const float* L = lines[k];
        size_t hw = (size_t)DIMSZ * DIMSZ;
        int b00 = iy0 * DIMSZ + ix0, b01 = iy0 * DIMSZ + ix1;
        int b10 = iy1 * DIMSZ + ix0, b11 = iy1 * DIMSZ + ix1;
        fvec4 r;
#pragma unroll
        for (int j = 0; j < 4; ++j) {
            size_t cb = (size_t)(q * 4 + j) * hw;
            float fp = P[cb + b00] * w00 + P[cb + b01] * w01 +
                       P[cb + b10] * w10 + P[cb + b11] * w11;
            size_t lb = (size_t)(q * 4 + j) * DIMSZ;
            float flv = L[lb + l0] * (1.f - wl) + L[lb + l1] * wl;
            r[j] = fp * flv;
        }
        out4[(size_t)k * NPTS * 4 + (size_t)i * 4 + q] = r;
    }
}

// ---------------------------------------------------------------------------
extern "C" void kernel_launch(void* const* d_in, const int* in_sizes, int n_in,
                              void* d_out, int out_size, void* d_ws, size_t ws_size,
                              hipStream_t stream)
{
    const float* coords_plane = (const float*)d_in[0];
    const float* coords_line  = (const float*)d_in[1];
    const float* pxy = (const float*)d_in[2];
    const float* pyz = (const float*)d_in[3];
    const float* pxz = (const float*)d_in[4];
    const float* lx  = (const float*)d_in[5];
    const float* ly  = (const float*)d_in[6];
    const float* lz  = (const float*)d_in[7];
    float* out = (float*)d_out;

    const size_t planeH = (size_t)DIMSZ * DIMSZ * CCH;   // halves per plane
    const size_t lineF  = (size_t)DIMSZ * CCH;           // floats per line
    const size_t needBytes = 3 * planeH * sizeof(_Float16) + 3 * lineF * sizeof(float);

    if (ws_size >= needBytes) {
        char* w = (char*)d_ws;
        _Float16* txy = (_Float16*)w;
        _Float16* tyz = txy + planeH;
        _Float16* txz = tyz + planeH;
        float* tlx = (float*)(w + 3 * planeH * sizeof(_Float16));
        float* tly = tlx + lineF;
        float* tlz = tly + lineF;

        dim3 gp((DIMSZ * DIMSZ + 63) / 64, 3);
        transpose_planes<<<gp, 256, 0, stream>>>(pxy, pyz, pxz, txy, tyz, txz);
        dim3 gl(1, 3);
        transpose_lines<<<gl, 256, 0, stream>>>(lx, ly, lz, tlx, tly, tlz);

        const int blocks = (NPTS * 4 + 255) / 256;
        td_plane<0><<<blocks, 256, 0, stream>>>(coords_plane, coords_line, tyz, tlx, out);
        td_plane<1><<<blocks, 256, 0, stream>>>(coords_plane, coords_line, txz, tly, out);
        td_plane<2><<<blocks, 256, 0, stream>>>(coords_plane, coords_line, txy, tlz, out);
    } else {
        const int blocks = (NPTS * 4 + 255) / 256;
        td_fallback<<<blocks, 256, 0, stream>>>(coords_plane, coords_line,
                                                pxy, pyz, pxz, lx, ly, lz, out);
    }
}

// Round 10
// 131.372 us; speedup vs baseline: 1.7856x; 1.7856x over previous
//
#include <hip/hip_runtime.h>

#define DIMSZ 300
#define CCH   16
#define NPTS  1048576
#define HW    (DIMSZ * DIMSZ)

typedef _Float16 half8 __attribute__((ext_vector_type(8)));
typedef float    fvec4 __attribute__((ext_vector_type(4)));
typedef float    fvec2 __attribute__((ext_vector_type(2)));

// ---------------------------------------------------------------------------
// Quad-record builder: source (C,H,W) f32 -> records[y*300+x] of 128 B:
//   for cq in 0..3:  [c00(4h) c01(4h)] [c10(4h) c11(4h)]   (2 x half8)
// where c00=(y,x) c01=(y,x1) c10=(y1,x) c11=(y1,x1), x1=min(x+1,299),
// y1=min(y+1,299), channels cq*4..cq*4+3, fp16.
// Thread = (record, cq). blockIdx.y selects plane.
// ---------------------------------------------------------------------------
__global__ __launch_bounds__(256) void build_quads(
    const float* __restrict__ a, const float* __restrict__ b, const float* __restrict__ c,
    _Float16* __restrict__ ta, _Float16* __restrict__ tb, _Float16* __restrict__ tc)
{
    const float* in  = (blockIdx.y == 0) ? a  : (blockIdx.y == 1) ? b  : c;
    _Float16*    out = (blockIdx.y == 0) ? ta : (blockIdx.y == 1) ? tb : tc;

    int idx = blockIdx.x * 256 + threadIdx.x;
    int rec = idx >> 2;
    int cq  = idx & 3;
    if (rec >= HW) return;

    int y  = rec / DIMSZ;
    int x  = rec - y * DIMSZ;
    int x1 = min(x + 1, DIMSZ - 1);
    int y1 = min(y + 1, DIMSZ - 1);

    int p00 = y  * DIMSZ + x,  p01 = y  * DIMSZ + x1;
    int p10 = y1 * DIMSZ + x,  p11 = y1 * DIMSZ + x1;

    half8 A, B;
#pragma unroll
    for (int j = 0; j < 4; ++j) {
        size_t cb = (size_t)(cq * 4 + j) * HW;
        A[j]     = (_Float16)in[cb + p00];
        A[4 + j] = (_Float16)in[cb + p01];
        B[j]     = (_Float16)in[cb + p10];
        B[4 + j] = (_Float16)in[cb + p11];
    }
    half8* o8 = (half8*)out;
    o8[(size_t)rec * 8 + cq * 2]     = A;
    o8[(size_t)rec * 8 + cq * 2 + 1] = B;
}

// ---------------------------------------------------------------------------
// Lines: (C, H) f32 -> (H, C) f32.  Tiny.
// ---------------------------------------------------------------------------
__global__ __launch_bounds__(256) void transpose_lines(
    const float* __restrict__ a, const float* __restrict__ b, const float* __restrict__ c,
    float* __restrict__ ta, float* __restrict__ tb, float* __restrict__ tc)
{
    const float* in  = (blockIdx.y == 0) ? a  : (blockIdx.y == 1) ? b  : c;
    float*       out = (blockIdx.y == 0) ? ta : (blockIdx.y == 1) ? tb : tc;
    for (int idx = threadIdx.x; idx < DIMSZ * CCH; idx += 256) {
        int p  = idx >> 4;
        int ch = idx & 15;
        out[idx] = in[ch * DIMSZ + p];
    }
}

// ---------------------------------------------------------------------------
// Per-plane main kernel. K = output slot (0: yz*x, 1: xz*y, 2: xy*z).
// One thread per (sample, channel-quad). Lane q reads 32 B (2 x half8) of the
// sample's single 128-B quad record: ONE L1 line-miss per sample per plane.
// All 4 corners arrive in-lane; no shuffles.
// ---------------------------------------------------------------------------
template <int K>
__global__ __launch_bounds__(256) void td_plane(
    const float* __restrict__ coords_plane,
    const float* __restrict__ coords_line,
    const _Float16* __restrict__ ptex,
    const float* __restrict__ ltex,
    float* __restrict__ out)
{
    int gid = blockIdx.x * 256 + threadIdx.x;
    int i = gid >> 2;
    int q = gid & 3;
    if (i >= NPTS) return;

    // out_x uses plane coords slice 1 (yz), out_y slice 2 (xz), out_z slice 0 (xy)
    constexpr int PC = (K == 0) ? 1 : (K == 1) ? 2 : 0;

    const fvec2* cp = (const fvec2*)coords_plane;
    const fvec2* cl = (const fvec2*)coords_line;
    fvec2 g  = cp[(size_t)PC * NPTS + i];
    float gl = cl[(size_t)K * NPTS + i].y;   // lines use grid[:,1] (W==1)

    // ---- plane bilinear (W = H = 300) ----
    float ix = (g.x + 1.f) * 0.5f * (float)(DIMSZ - 1);
    float iy = (g.y + 1.f) * 0.5f * (float)(DIMSZ - 1);
    float ix0f = floorf(ix), iy0f = floorf(iy);
    float wx = ix - ix0f, wy = iy - iy0f;
    // coords in [-1,1) => ix0,iy0 in [0,298]; clamps are safety no-ops and
    // match reference (record stores x1=min(x+1,299), y1=min(y+1,299))
    int ix0 = min(max((int)ix0f, 0), DIMSZ - 2);
    int iy0 = min(max((int)iy0f, 0), DIMSZ - 2);

    const half8* t8 = (const half8*)ptex;
    size_t base8 = ((size_t)iy0 * DIMSZ + ix0) * 8 + q * 2;
    half8 A = t8[base8];       // [c00 | c01]
    half8 B = t8[base8 + 1];   // [c10 | c11]

    float w00 = (1.f - wx) * (1.f - wy);
    float w01 = wx * (1.f - wy);
    float w10 = (1.f - wx) * wy;
    float w11 = wx * wy;

    fvec4 f;
#pragma unroll
    for (int j = 0; j < 4; ++j) {
        f[j] = (float)A[j]     * w00 + (float)A[4 + j] * w01 +
               (float)B[j]     * w10 + (float)B[4 + j] * w11;
    }

    // ---- line linear (H = 300), f32 (H,C), L1-resident ----
    float lyv = (gl + 1.f) * 0.5f * (float)(DIMSZ - 1);
    float ly0f = floorf(lyv);
    float wl = lyv - ly0f;
    int l0 = min(max((int)ly0f, 0), DIMSZ - 1);
    int l1 = min(l0 + 1, DIMSZ - 1);

    const fvec4* l4 = (const fvec4*)ltex;
    fvec4 u0 = l4[(size_t)l0 * 4 + q];
    fvec4 u1 = l4[(size_t)l1 * 4 + q];
    fvec4 fl = u0 * (1.f - wl) + u1 * wl;

    fvec4* out4 = (fvec4*)out;
    out4[(size_t)K * NPTS * 4 + (size_t)i * 4 + q] = f * fl;
}

// ---------------------------------------------------------------------------
// Fallback (no usable ws): direct f32 gather from original (C,H,W) layout.
// ---------------------------------------------------------------------------
__global__ __launch_bounds__(256) void td_fallback(
    const float* __restrict__ coords_plane,
    const float* __restrict__ coords_line,
    const float* __restrict__ pxy, const float* __restrict__ pyz,
    const float* __restrict__ pxz,
    const float* __restrict__ lx, const float* __restrict__ ly,
    const float* __restrict__ lz,
    float* __restrict__ out)
{
    int gid = blockIdx.x * 256 + threadIdx.x;
    int i = gid >> 2;
    int q = gid & 3;
    if (i >= NPTS) return;

    const fvec2* cp = (const fvec2*)coords_plane;
    const fvec2* cl = (const fvec2*)coords_line;

    fvec4* out4 = (fvec4*)out;
    const float* planes[3] = {pyz, pxz, pxy};
    const float* lines[3]  = {lx, ly, lz};
    const int    pcs[3]    = {1, 2, 0};

#pragma unroll
    for (int k = 0; k < 3; ++k) {
        fvec2 g  = cp[(size_t)pcs[k] * NPTS + i];
        float gl = cl[(size_t)k * NPTS + i].y;

        float ix = (g.x + 1.f) * 0.5f * (float)(DIMSZ - 1);
        float iy = (g.y + 1.f) * 0.5f * (float)(DIMSZ - 1);
        float ix0f = floorf(ix), iy0f = floorf(iy);
        float wx = ix - ix0f, wy = iy - iy0f;
        int ix0 = min(max((int)ix0f, 0), DIMSZ - 1);
        int ix1 = min(ix0 + 1, DIMSZ - 1);
        int iy0 = min(max((int)iy0f, 0), DIMSZ - 1);
        int iy1 = min(iy0 + 1, DIMSZ - 1);
        float w00 = (1.f - wx) * (1.f - wy), w01 = wx * (1.f - wy);
        float w10 = (1.f - wx) * wy,         w11 = wx * wy;

        float lyv = (gl + 1.f) * 0.5f * (float)(DIMSZ - 1);
        float ly0f = floorf(lyv);
        float wl = lyv - ly0f;
        int l0 = min(max((int)ly0f, 0), DIMSZ - 1);
        int l1 = min(l0 + 1, DIMSZ - 1);

        const float* P = planes[k];
        const float* L = lines[k];
        int b00 = iy0 * DIMSZ + ix0, b01 = iy0 * DIMSZ + ix1;
        int b10 = iy1 * DIMSZ + ix0, b11 = iy1 * DIMSZ + ix1;
        fvec4 r;
#pragma unroll
        for (int j = 0; j < 4; ++j) {
            size_t cb = (size_t)(q * 4 + j) * HW;
            float fp = P[cb + b00] * w00 + P[cb + b01] * w01 +
                       P[cb + b10] * w10 + P[cb + b11] * w11;
            size_t lb = (size_t)(q * 4 + j) * DIMSZ;
            float flv = L[lb + l0] * (1.f - wl) + L[lb + l1] * wl;
            r[j] = fp * flv;
        }
        out4[(size_t)k * NPTS * 4 + (size_t)i * 4 + q] = r;
    }
}

// ---------------------------------------------------------------------------
extern "C" void kernel_launch(void* const* d_in, const int* in_sizes, int n_in,
                              void* d_out, int out_size, void* d_ws, size_t ws_size,
                              hipStream_t stream)
{
    const float* coords_plane = (const float*)d_in[0];
    const float* coords_line  = (const float*)d_in[1];
    const float* pxy = (const float*)d_in[2];
    const float* pyz = (const float*)d_in[3];
    const float* pxz = (const float*)d_in[4];
    const float* lx  = (const float*)d_in[5];
    const float* ly  = (const float*)d_in[6];
    const float* lz  = (const float*)d_in[7];
    float* out = (float*)d_out;

    const size_t planeQH = (size_t)HW * 64;          // halves per quad-plane (128 B/record)
    const size_t lineF   = (size_t)DIMSZ * CCH;      // floats per line
    const size_t needBytes = 3 * planeQH * sizeof(_Float16) + 3 * lineF * sizeof(float);

    if (ws_size >= needBytes) {
        char* w = (char*)d_ws;
        _Float16* txy = (_Float16*)w;
        _Float16* tyz = txy + planeQH;
        _Float16* txz = tyz + planeQH;
        float* tlx = (float*)(w + 3 * planeQH * sizeof(_Float16));
        float* tly = tlx + lineF;
        float* tlz = tly + lineF;

        dim3 gq((HW * 4 + 255) / 256, 3);
        build_quads<<<gq, 256, 0, stream>>>(pxy, pyz, pxz, txy, tyz, txz);
        dim3 gl(1, 3);
        transpose_lines<<<gl, 256, 0, stream>>>(lx, ly, lz, tlx, tly, tlz);

        const int blocks = (NPTS * 4 + 255) / 256;
        td_plane<0><<<blocks, 256, 0, stream>>>(coords_plane, coords_line, tyz, tlx, out);
        td_plane<1><<<blocks, 256, 0, stream>>>(coords_plane, coords_line, txz, tly, out);
        td_plane<2><<<blocks, 256, 0, stream>>>(coords_plane, coords_line, txy, tlz, out);
    } else {
        const int blocks = (NPTS * 4 + 255) / 256;
        td_fallback<<<blocks, 256, 0, stream>>>(coords_plane, coords_line,
                                                pxy, pyz, pxz, lx, ly, lz, out);
    }
}